// Round 14
// baseline (194.606 us; speedup 1.0000x reference)
//
#include <hip/hip_runtime.h>

#define B_    8
#define C_    1024
#define HID   64
#define N_    2048
#define RTOT  192

typedef __attribute__((ext_vector_type(8))) short   bf16x8;
typedef __attribute__((ext_vector_type(4))) unsigned short ush4;
typedef __attribute__((ext_vector_type(4))) float   f32x4;
typedef __attribute__((ext_vector_type(16))) float  f32x16;

// ---- workspace byte offsets ----
#define WSB_WBF   ((size_t)0)          // [192][1024]     bf16
#define WSB_THT   ((size_t)6684672)    // [B][2048][64]   bf16
#define WSB_M     ((size_t)8781824)    // [B][64][64]     f32
#define WSB_G     ((size_t)8912896)    // [B][64][64]     f32
#define WSB_S     ((size_t)9043968)    // [B][64]         f32 (contiguous after G)
#define WSB_WMBF  ((size_t)9046016)    // [B][1024][64]   bf16
#define WSB_SC    ((size_t)10094592)   // [1024] f32
#define WSB_SH    ((size_t)10098688)   // [1024] f32

#define MGS_FLOATS (2 * B_ * HID * HID + B_ * HID)   // 66048

static __device__ __forceinline__ unsigned short f2bf(float f) {
    union { float f; unsigned u; } v; v.f = f;
    unsigned r = v.u + 0x7fffu + ((v.u >> 16) & 1u);
    return (unsigned short)(r >> 16);
}
static __device__ __forceinline__ float bf2f(unsigned short h) {
    union { unsigned u; float f; } v; v.u = ((unsigned)h) << 16;
    return v.f;
}

// async global->LDS DMA, 16B per lane. LDS dest must be linear in lane order.
static __device__ __forceinline__ void gload16(const unsigned short* g, unsigned short* l) {
    __builtin_amdgcn_global_load_lds(
        (const __attribute__((address_space(1))) unsigned int*)g,
        (__attribute__((address_space(3))) unsigned int*)l, 16, 0, 0);
}

// K0: weights -> bf16 (concat theta/phi/g) + zero M|G|S (absorbs the memset).
__global__ __launch_bounds__(256) void wcvt(
    const float* __restrict__ tw, const float* __restrict__ pw,
    const float* __restrict__ gw, unsigned short* __restrict__ wbf,
    float* __restrict__ mgs)
{
    int idx = blockIdx.x * 256 + threadIdx.x;
    if (blockIdx.x < 258) {
        int z = blockIdx.x * 256 + threadIdx.x;
        if (z < MGS_FLOATS) mgs[z] = 0.f;
    }
    int r = idx >> 10, k = idx & 1023;
    float v = (r < 64) ? tw[(size_t)r * 1024 + k]
            : (r < 128) ? pw[(size_t)(r - 64) * 1024 + k]
                        : gw[(size_t)(r - 128) * 1024 + k];
    wbf[idx] = f2bf(v);
}

// K1: fused transpose + projection GEMM + GRAM (gram kernel absorbed).
// Block = 32n x 192r, grid 64 x 8. T4 counted-vmcnt pipeline as r12.
// Epilogue: bias-add -> stash bf16 tile to LDS P[192][40] -> per-wave
// 16x16x32 MFMAs compute this n-slice's partials of M = phi·g^T,
// G = theta·theta^T, S = theta·1 -> atomicAdd into zeroed M|G|S.
// FIX vs r13: epilogue barriers are __syncthreads() (waitcnt+fence) —
// raw s_barrier after the Pls stores raced (no lgkmcnt drain, no
// compiler memory fence; ISA rule "s_waitcnt first if data dep").
__global__ __launch_bounds__(256, 2) void projx_mfma(
    const float* __restrict__ x, const unsigned short* __restrict__ wbf,
    const float* __restrict__ tb, const float* __restrict__ pb,
    const float* __restrict__ gb, unsigned short* __restrict__ thT,
    float* __restrict__ Mm, float* __restrict__ Gg, float* __restrict__ S)
{
    const int b = blockIdx.y, n0 = blockIdx.x * 32;
    const int t = threadIdx.x, w = t >> 6, L = t & 63;
    const int wn = w & 1, wc = w >> 1;          // wc in {0,1}: 96-row half
    const int lr = L & 15, q = L >> 4;

    typedef unsigned short AbufT[2][32][64];    // 8 KB
    typedef unsigned short BbufT[2][192][64];   // 48 KB
    typedef unsigned short PT[192][40];         // 15 KB (aliases smem base)
    __shared__ __align__(16) char smem[57344];
    AbufT& Abuf = *reinterpret_cast<AbufT*>(smem);
    BbufT& Bbuf = *reinterpret_cast<BbufT*>(smem + 8192);
    PT&    Pls  = *reinterpret_cast<PT*>(smem);

    f32x4 acc[6] = {};

    // x staging: thread covers c-pair g (rows 2g,2g+1), n-quad n4.
    const int n4 = t & 7;        // 0..7  (n_local = 4*n4..4*n4+3)
    const int g  = t >> 3;       // 0..31 (c-pair)
    const float* xbase = x + (size_t)b * C_ * N_ + n0 + n4 * 4;

    f32x4 vr[2];
    auto loadX = [&](int s) {
        const float* p = xbase + (size_t)(64 * s + 2 * g) * N_;
        vr[0] = *(const f32x4*)(p);
        vr[1] = *(const f32x4*)(p + N_);
    };
    auto writeA = [&](int cb) {
#pragma unroll
        for (int rrow = 0; rrow < 4; rrow++) {
            int n  = 4 * n4 + rrow;              // 0..31
            int sw = (n ^ (n >> 3)) & 7;
            int ss = (g >> 2) ^ sw;
            unsigned val = (unsigned)f2bf(vr[0][rrow]) | ((unsigned)f2bf(vr[1][rrow]) << 16);
            ((unsigned*)&Abuf[cb][n][0])[ss * 4 + (g & 3)] = val;
        }
    };
    auto stageB = [&](int cb, int s) {
        const int k0 = 64 * s;
#pragma unroll
        for (int i = 0; i < 6; i++) {            // B: 24 KB = 6 chunks
            int o = (i * 256 + t) * 16;
            int row = o >> 7, slot = (o >> 4) & 7, ss = slot ^ (row & 7);
            gload16(wbf + ((size_t)row) * 1024 + k0 + ss * 8,
                    &Bbuf[cb][0][0] + o / 2);
        }
    };

    const int swB = lr & 7;
    const int nfa = wn * 16 + lr;                // 0..31
    const int swA = (nfa ^ (nfa >> 3)) & 7;
    auto compute = [&](int cur) {
#pragma unroll
        for (int ksub = 0; ksub < 2; ksub++) {
            bf16x8 Af = *(const bf16x8*)&Abuf[cur][nfa][((ksub * 4 + q) ^ swA) * 8];
            bf16x8 Bf[6];
#pragma unroll
            for (int j = 0; j < 6; j++)
                Bf[j] = *(const bf16x8*)&Bbuf[cur][wc * 96 + j * 16 + lr]
                                              [((ksub * 4 + q) ^ swB) * 8];
#pragma unroll
            for (int j = 0; j < 6; j++)
                acc[j] = __builtin_amdgcn_mfma_f32_16x16x32_bf16(
                    Af, Bf[j], acc[j], 0, 0, 0);
        }
    };

    // ---- prologue ----
    loadX(0);
    asm volatile("s_waitcnt vmcnt(0)" ::: "memory");
    writeA(0);
    stageB(0, 0);                 // 6 ops
    loadX(1);                     // 2 ops -> 8 outstanding
    asm volatile("s_waitcnt vmcnt(2)" ::: "memory");   // B0 landed, X1 flying
    asm volatile("s_waitcnt lgkmcnt(0)" ::: "memory");
    __builtin_amdgcn_s_barrier();

    int cur = 0;
    for (int s = 0; s < 16; s++) {
        if (s < 15) {
            writeA(cur ^ 1);      // consumes X(s+1)
            stageB(cur ^ 1, s + 1);
        }
        if (s < 14) loadX(s + 2);
        compute(cur);
        if (s < 14)
            asm volatile("s_waitcnt vmcnt(2)" ::: "memory");  // B(s+1) done
        else
            asm volatile("s_waitcnt vmcnt(0)" ::: "memory");
        asm volatile("s_waitcnt lgkmcnt(0)" ::: "memory");
        if (s < 15) __builtin_amdgcn_s_barrier();
        cur ^= 1;
    }

    // ---- epilogue part 1: bias add, stash P to LDS, theta -> thT ----
    __syncthreads();            // all waves done reading A/B bufs (fence + wait)

#pragma unroll
    for (int j = 0; j < 6; j++) {
        int rcol = 96 * wc + 16 * j + lr;
        float bias = (rcol < 64) ? tb[rcol]
                   : (rcol < 128) ? pb[rcol - 64] : gb[rcol - 128];
        ush4 o;
#pragma unroll
        for (int rr = 0; rr < 4; rr++) o[rr] = f2bf(acc[j][rr] + bias);
        int nl = 16 * wn + q * 4;
        *(ush4*)&Pls[rcol][nl] = o;
        if (rcol < HID) {   // theta rows: transposed copy for finalk
            int nglob = n0 + nl;
#pragma unroll
            for (int rr = 0; rr < 4; rr++)
                thT[((size_t)b * N_ + nglob + rr) * HID + rcol] = o[rr];
        }
    }
    __syncthreads();            // Pls writes visible to all waves (fence + wait)

    // ---- epilogue part 2: fused gram (k = 32 n-slice in ONE MFMA) ----
    // wave w: M rows [16w,16w+16) = phi(64+16w..) · g^T ; G rows = theta·theta^T
    bf16x8 ones;
#pragma unroll
    for (int j = 0; j < 8; j++) ones[j] = (short)0x3F80;

    bf16x8 Aphi = *(const bf16x8*)&Pls[64 + 16 * w + lr][q * 8];
    bf16x8 Ath  = *(const bf16x8*)&Pls[16 * w + lr][q * 8];

    f32x4 aM[4] = {}, aG[4] = {}, aS = {};
#pragma unroll
    for (int gt = 0; gt < 4; gt++) {
        bf16x8 Bg = *(const bf16x8*)&Pls[128 + 16 * gt + lr][q * 8];
        bf16x8 Bt = *(const bf16x8*)&Pls[16 * gt + lr][q * 8];
        aM[gt] = __builtin_amdgcn_mfma_f32_16x16x32_bf16(Aphi, Bg, aM[gt], 0, 0, 0);
        aG[gt] = __builtin_amdgcn_mfma_f32_16x16x32_bf16(Ath,  Bt, aG[gt], 0, 0, 0);
    }
    aS = __builtin_amdgcn_mfma_f32_16x16x32_bf16(Ath, ones, aS, 0, 0, 0);

    float* Mb = Mm + (size_t)b * HID * HID;
    float* Gb = Gg + (size_t)b * HID * HID;
#pragma unroll
    for (int gt = 0; gt < 4; gt++)
#pragma unroll
        for (int rr = 0; rr < 4; rr++) {
            int row = 16 * w + 4 * q + rr, col = 16 * gt + lr;
            atomicAdd(Mb + row * HID + col, aM[gt][rr]);
            atomicAdd(Gb + row * HID + col, aG[gt][rr]);
        }
    if (lr == 0) {
#pragma unroll
        for (int rr = 0; rr < 4; rr++)
            atomicAdd(S + b * HID + 16 * w + 4 * q + rr, aS[rr]);
    }
}

// K3: fused wmk + statsk, 4 channels per block (grid 256). Each thread
// register-caches its M-row and G-row ONCE, reused for 4 channels.
__global__ __launch_bounds__(512, 1) void wmstat(
    const float* __restrict__ ww, const float* __restrict__ Mm,
    const float* __restrict__ S, const float* __restrict__ G,
    const float* __restrict__ wb, const float* __restrict__ gamma,
    const float* __restrict__ beta, unsigned short* __restrict__ wmbf,
    float* __restrict__ scale, float* __restrict__ shift2)
{
    const int c0 = blockIdx.x * 4;
    const int t = threadIdx.x;
    const int b = t >> 6, lane = t & 63;

    f32x4 mrow[16], grow[16];
    {
        const f32x4* mr4 = (const f32x4*)(Mm + ((size_t)b * HID + lane) * HID);
        const f32x4* gr4 = (const f32x4*)(G  + (size_t)b * HID * HID + (size_t)lane * HID);
#pragma unroll
        for (int i = 0; i < 16; i++) mrow[i] = mr4[i];
#pragma unroll
        for (int i = 0; i < 16; i++) grow[i] = gr4[i];
    }
    const float sv = S[b * HID + lane];

    __shared__ float vsh[8][64];
    __shared__ float red[4][16];

#pragma unroll
    for (int ci = 0; ci < 4; ci++) {
        const int c = c0 + ci;
        const float wbc = wb[c];
        const float* wr = ww + (size_t)c * HID;

        float acc = 0.f;
#pragma unroll
        for (int d = 0; d < 16; d++) {
            f32x4 w4 = *(const f32x4*)(wr + 4 * d);
            acc += w4[0] * mrow[d][0] + w4[1] * mrow[d][1]
                 + w4[2] * mrow[d][2] + w4[3] * mrow[d][3];
        }
        unsigned short us = f2bf(acc * (1.0f / N_));
        wmbf[((size_t)b * C_ + c) * HID + lane] = us;
        float v = bf2f(us);
        float t1 = v * sv;
        for (int off = 32; off; off >>= 1) t1 += __shfl_down(t1, off);
        t1 = __shfl(t1, 0);

        __syncthreads();
        vsh[b][lane] = v;
        __syncthreads();

        const f32x4* vb4 = (const f32x4*)&vsh[b][0];
        float inner = 0.f;
#pragma unroll
        for (int fo = 0; fo < 16; fo++) {
            f32x4 vv = vb4[fo];
            inner = fmaf(grow[fo][0], vv[0], inner);
            inner = fmaf(grow[fo][1], vv[1], inner);
            inner = fmaf(grow[fo][2], vv[2], inner);
            inner = fmaf(grow[fo][3], vv[3], inner);
        }
        float qq = v * inner;
        for (int off = 32; off; off >>= 1) qq += __shfl_down(qq, off);
        qq = __shfl(qq, 0);

        if (lane == 0) {
            red[ci][b] = t1;
            red[ci][8 + b] = qq + 2.f * wbc * t1;
        }
    }
    __syncthreads();
    if (t < 4) {
        const int c = c0 + t;
        float asum = 0.f, asq = 0.f;
#pragma unroll
        for (int i = 0; i < 8; i++) { asum += red[t][i]; asq += red[t][8 + i]; }
        const float wbc = wb[c];
        const float cnt = (float)B_ * (float)N_;
        const float inv = 1.0f / cnt;
        float mean = (asum + cnt * wbc) * inv;
        float e2   = (asq + cnt * wbc * wbc) * inv;
        float var  = e2 - mean * mean;
        float sc   = gamma[c] * rsqrtf(var + 1e-5f);
        scale[c]  = sc;
        shift2[c] = beta[c] - mean * sc + sc * wbc;
    }
}

// K4: out = sc[c]*(Wm[b][c][:]·theta[:,n]) + sh[c] + x.
// 32x32x16 MFMA; per-instruction x/out access = 2x128B contiguous.
__global__ __launch_bounds__(256) void finalk_mfma(
    const unsigned short* __restrict__ wmbf, const unsigned short* __restrict__ thT,
    const float* __restrict__ x, const float* __restrict__ scale,
    const float* __restrict__ shift2, float* __restrict__ out)
{
    const int b = blockIdx.z, c0 = blockIdx.y * 32, n0b = blockIdx.x * 128;
    const int t = threadIdx.x, w = t >> 6, L = t & 63;
    const int n0 = n0b + w * 32;
    const int rr = L & 31, kh = L >> 5;

    const unsigned short* apw = wmbf + ((size_t)b * C_ + c0 + rr) * HID + kh * 8;
    const unsigned short* bpt = thT + ((size_t)b * N_ + n0 + rr) * HID + kh * 8;

    float xv[16];
#pragma unroll
    for (int r = 0; r < 16; r++) {
        int cl = (r & 3) + 8 * (r >> 2) + 4 * kh;
        xv[r] = x[((size_t)b * C_ + c0 + cl) * N_ + n0 + rr];
    }

    f32x16 acc = {};
#pragma unroll
    for (int kk = 0; kk < 4; kk++) {
        bf16x8 A  = *(const bf16x8*)(apw + kk * 16);
        bf16x8 Bv = *(const bf16x8*)(bpt + kk * 16);
        acc = __builtin_amdgcn_mfma_f32_32x32x16_bf16(A, Bv, acc, 0, 0, 0);
    }

#pragma unroll
    for (int r = 0; r < 16; r++) {
        int cl = (r & 3) + 8 * (r >> 2) + 4 * kh;
        int c  = c0 + cl;
        size_t off = ((size_t)b * C_ + c) * N_ + n0 + rr;
        out[off] = fmaf(scale[c], acc[r], shift2[c]) + xv[r];
    }
}

extern "C" void kernel_launch(void* const* d_in, const int* in_sizes, int n_in,
                              void* d_out, int out_size, void* d_ws, size_t ws_size,
                              hipStream_t stream)
{
    const float* x  = (const float*)d_in[0];
    const float* tw = (const float*)d_in[1];
    const float* tb = (const float*)d_in[2];
    const float* pw = (const float*)d_in[3];
    const float* pb = (const float*)d_in[4];
    const float* gw = (const float*)d_in[5];
    const float* gb = (const float*)d_in[6];
    const float* ww = (const float*)d_in[7];
    const float* wb = (const float*)d_in[8];
    const float* gamma = (const float*)d_in[9];
    const float* beta  = (const float*)d_in[10];
    float* out = (float*)d_out;

    char* ws = (char*)d_ws;
    unsigned short* wbf   = (unsigned short*)(ws + WSB_WBF);
    unsigned short* thT   = (unsigned short*)(ws + WSB_THT);
    float* Mm   = (float*)(ws + WSB_M);
    float* Gg   = (float*)(ws + WSB_G);
    float* S    = (float*)(ws + WSB_S);
    unsigned short* wmbf = (unsigned short*)(ws + WSB_WMBF);
    float* scl  = (float*)(ws + WSB_SC);
    float* shf  = (float*)(ws + WSB_SH);

    wcvt<<<dim3(RTOT * 1024 / 256), 256, 0, stream>>>(tw, pw, gw, wbf, Mm);
    projx_mfma<<<dim3(64, B_), 256, 0, stream>>>(x, wbf, tb, pb, gb, thT, Mm, Gg, S);
    wmstat<<<C_ / 4, 512, 0, stream>>>(ww, Mm, S, Gg, wb, gamma, beta, wmbf, scl, shf);
    finalk_mfma<<<dim3(16, 32, B_), 256, 0, stream>>>(wmbf, thT, x, scl, shf, out);
}

// Round 15
// 194.519 us; speedup vs baseline: 1.0005x; 1.0005x over previous
//
#include <hip/hip_runtime.h>

#define B_    8
#define C_    1024
#define HID   64
#define N_    2048
#define RTOT  192

typedef __attribute__((ext_vector_type(8))) short   bf16x8;
typedef __attribute__((ext_vector_type(4))) unsigned short ush4;
typedef __attribute__((ext_vector_type(4))) float   f32x4;
typedef __attribute__((ext_vector_type(16))) float  f32x16;

// ---- workspace byte offsets ----
#define WSB_WBF   ((size_t)0)          // [192][1024]     bf16
#define WSB_THT   ((size_t)6684672)    // [B][2048][64]   bf16
#define WSB_M     ((size_t)8781824)    // [B][64][64]     f32
#define WSB_G     ((size_t)8912896)    // [B][64][64]     f32
#define WSB_S     ((size_t)9043968)    // [B][64]         f32 (contiguous after G)
#define WSB_WMBF  ((size_t)9046016)    // [B][1024][64]   bf16
#define WSB_SC    ((size_t)10094592)   // [1024] f32
#define WSB_SH    ((size_t)10098688)   // [1024] f32

#define MGS_FLOATS (2 * B_ * HID * HID + B_ * HID)   // 66048

static __device__ __forceinline__ unsigned short f2bf(float f) {
    union { float f; unsigned u; } v; v.f = f;
    unsigned r = v.u + 0x7fffu + ((v.u >> 16) & 1u);
    return (unsigned short)(r >> 16);
}
static __device__ __forceinline__ float bf2f(unsigned short h) {
    union { unsigned u; float f; } v; v.u = ((unsigned)h) << 16;
    return v.f;
}

// async global->LDS DMA, 16B per lane. LDS dest must be linear in lane order.
static __device__ __forceinline__ void gload16(const unsigned short* g, unsigned short* l) {
    __builtin_amdgcn_global_load_lds(
        (const __attribute__((address_space(1))) unsigned int*)g,
        (__attribute__((address_space(3))) unsigned int*)l, 16, 0, 0);
}

// K0: weights -> bf16 (concat theta/phi/g) + zero M|G|S (absorbs the memset).
__global__ __launch_bounds__(256) void wcvt(
    const float* __restrict__ tw, const float* __restrict__ pw,
    const float* __restrict__ gw, unsigned short* __restrict__ wbf,
    float* __restrict__ mgs)
{
    int idx = blockIdx.x * 256 + threadIdx.x;
    if (blockIdx.x < 258) {
        int z = blockIdx.x * 256 + threadIdx.x;
        if (z < MGS_FLOATS) mgs[z] = 0.f;
    }
    int r = idx >> 10, k = idx & 1023;
    float v = (r < 64) ? tw[(size_t)r * 1024 + k]
            : (r < 128) ? pw[(size_t)(r - 64) * 1024 + k]
                        : gw[(size_t)(r - 128) * 1024 + k];
    wbf[idx] = f2bf(v);
}

// K1: fused transpose + projection GEMM + GRAM.
// Block = 32n x 192r, grid 64 x 8. T4 counted-vmcnt pipeline.
// NEW vs r14: 2-DEEP X register pipeline (va/vb ping-pong, full unroll so
// buffer selection is compile-time). X loads get ~2 steps of flight instead
// of <1 compute-phase — removes the ~700cy/step writeA stall that kept
// projx at 46us (MfmaUtil 4.9, BW 1.16 TB/s).
__global__ __launch_bounds__(256, 2) void projx_mfma(
    const float* __restrict__ x, const unsigned short* __restrict__ wbf,
    const float* __restrict__ tb, const float* __restrict__ pb,
    const float* __restrict__ gb, unsigned short* __restrict__ thT,
    float* __restrict__ Mm, float* __restrict__ Gg, float* __restrict__ S)
{
    const int b = blockIdx.y, n0 = blockIdx.x * 32;
    const int t = threadIdx.x, w = t >> 6, L = t & 63;
    const int wn = w & 1, wc = w >> 1;          // wc in {0,1}: 96-row half
    const int lr = L & 15, q = L >> 4;

    typedef unsigned short AbufT[2][32][64];    // 8 KB
    typedef unsigned short BbufT[2][192][64];   // 48 KB
    typedef unsigned short PT[192][40];         // 15 KB (aliases smem base)
    __shared__ __align__(16) char smem[57344];
    AbufT& Abuf = *reinterpret_cast<AbufT*>(smem);
    BbufT& Bbuf = *reinterpret_cast<BbufT*>(smem + 8192);
    PT&    Pls  = *reinterpret_cast<PT*>(smem);

    f32x4 acc[6] = {};

    // x staging: thread covers c-pair g (rows 2g,2g+1), n-quad n4.
    const int n4 = t & 7;        // 0..7  (n_local = 4*n4..4*n4+3)
    const int g  = t >> 3;       // 0..31 (c-pair)
    const float* xbase = x + (size_t)b * C_ * N_ + n0 + n4 * 4;

    f32x4 va[2], vb[2];          // 2-deep X pipeline buffers
    auto loadXto = [&](int s, f32x4* dst) {
        const float* p = xbase + (size_t)(64 * s + 2 * g) * N_;
        dst[0] = *(const f32x4*)(p);
        dst[1] = *(const f32x4*)(p + N_);
    };
    auto writeAfrom = [&](int cb, const f32x4* src) {
#pragma unroll
        for (int rrow = 0; rrow < 4; rrow++) {
            int n  = 4 * n4 + rrow;              // 0..31
            int sw = (n ^ (n >> 3)) & 7;
            int ss = (g >> 2) ^ sw;
            unsigned val = (unsigned)f2bf(src[0][rrow]) | ((unsigned)f2bf(src[1][rrow]) << 16);
            ((unsigned*)&Abuf[cb][n][0])[ss * 4 + (g & 3)] = val;
        }
    };
    auto stageB = [&](int cb, int s) {
        const int k0 = 64 * s;
#pragma unroll
        for (int i = 0; i < 6; i++) {            // B: 24 KB = 6 chunks
            int o = (i * 256 + t) * 16;
            int row = o >> 7, slot = (o >> 4) & 7, ss = slot ^ (row & 7);
            gload16(wbf + ((size_t)row) * 1024 + k0 + ss * 8,
                    &Bbuf[cb][0][0] + o / 2);
        }
    };

    const int swB = lr & 7;
    const int nfa = wn * 16 + lr;                // 0..31
    const int swA = (nfa ^ (nfa >> 3)) & 7;
    auto compute = [&](int cur) {
#pragma unroll
        for (int ksub = 0; ksub < 2; ksub++) {
            bf16x8 Af = *(const bf16x8*)&Abuf[cur][nfa][((ksub * 4 + q) ^ swA) * 8];
            bf16x8 Bf[6];
#pragma unroll
            for (int j = 0; j < 6; j++)
                Bf[j] = *(const bf16x8*)&Bbuf[cur][wc * 96 + j * 16 + lr]
                                              [((ksub * 4 + q) ^ swB) * 8];
#pragma unroll
            for (int j = 0; j < 6; j++)
                acc[j] = __builtin_amdgcn_mfma_f32_16x16x32_bf16(
                    Af, Bf[j], acc[j], 0, 0, 0);
        }
    };

    // ---- prologue: tile0 staged; X1,X2 in flight ----
    loadXto(0, va);
    asm volatile("s_waitcnt vmcnt(0)" ::: "memory");
    writeAfrom(0, va);
    stageB(0, 0);                 // 6 ops
    loadXto(1, va);               // X1 -> va (odd)
    loadXto(2, vb);               // X2 -> vb (even)
    asm volatile("s_waitcnt vmcnt(4)" ::: "memory");   // B0 landed; X1,X2 flying
    asm volatile("s_waitcnt lgkmcnt(0)" ::: "memory");
    __builtin_amdgcn_s_barrier();

    int cur = 0;
#pragma unroll
    for (int s = 0; s < 16; s++) {
        if (s < 15) {
            writeAfrom(cur ^ 1, ((s + 1) & 1) ? va : vb);   // X(s+1): retired last step
            stageB(cur ^ 1, s + 1);
        }
        if (s < 13) loadXto(s + 3, ((s + 3) & 1) ? va : vb); // refill freed buffer
        compute(cur);
        if (s < 13)
            asm volatile("s_waitcnt vmcnt(2)" ::: "memory"); // retire X(s+2)+B(s+1); X(s+3) flies
        else
            asm volatile("s_waitcnt vmcnt(0)" ::: "memory"); // tail drain
        asm volatile("s_waitcnt lgkmcnt(0)" ::: "memory");
        if (s < 15) __builtin_amdgcn_s_barrier();
        cur ^= 1;
    }

    // ---- epilogue part 1: bias add, stash P to LDS, theta -> thT ----
    __syncthreads();            // all waves done reading A/B bufs (fence + wait)

#pragma unroll
    for (int j = 0; j < 6; j++) {
        int rcol = 96 * wc + 16 * j + lr;
        float bias = (rcol < 64) ? tb[rcol]
                   : (rcol < 128) ? pb[rcol - 64] : gb[rcol - 128];
        ush4 o;
#pragma unroll
        for (int rr = 0; rr < 4; rr++) o[rr] = f2bf(acc[j][rr] + bias);
        int nl = 16 * wn + q * 4;
        *(ush4*)&Pls[rcol][nl] = o;
        if (rcol < HID) {   // theta rows: transposed copy for finalk
            int nglob = n0 + nl;
#pragma unroll
            for (int rr = 0; rr < 4; rr++)
                thT[((size_t)b * N_ + nglob + rr) * HID + rcol] = o[rr];
        }
    }
    __syncthreads();            // Pls writes visible to all waves (fence + wait)

    // ---- epilogue part 2: fused gram (k = 32 n-slice in ONE MFMA) ----
    bf16x8 ones;
#pragma unroll
    for (int j = 0; j < 8; j++) ones[j] = (short)0x3F80;

    bf16x8 Aphi = *(const bf16x8*)&Pls[64 + 16 * w + lr][q * 8];
    bf16x8 Ath  = *(const bf16x8*)&Pls[16 * w + lr][q * 8];

    f32x4 aM[4] = {}, aG[4] = {}, aS = {};
#pragma unroll
    for (int gt = 0; gt < 4; gt++) {
        bf16x8 Bg = *(const bf16x8*)&Pls[128 + 16 * gt + lr][q * 8];
        bf16x8 Bt = *(const bf16x8*)&Pls[16 * gt + lr][q * 8];
        aM[gt] = __builtin_amdgcn_mfma_f32_16x16x32_bf16(Aphi, Bg, aM[gt], 0, 0, 0);
        aG[gt] = __builtin_amdgcn_mfma_f32_16x16x32_bf16(Ath,  Bt, aG[gt], 0, 0, 0);
    }
    aS = __builtin_amdgcn_mfma_f32_16x16x32_bf16(Ath, ones, aS, 0, 0, 0);

    float* Mb = Mm + (size_t)b * HID * HID;
    float* Gb = Gg + (size_t)b * HID * HID;
#pragma unroll
    for (int gt = 0; gt < 4; gt++)
#pragma unroll
        for (int rr = 0; rr < 4; rr++) {
            int row = 16 * w + 4 * q + rr, col = 16 * gt + lr;
            atomicAdd(Mb + row * HID + col, aM[gt][rr]);
            atomicAdd(Gb + row * HID + col, aG[gt][rr]);
        }
    if (lr == 0) {
#pragma unroll
        for (int rr = 0; rr < 4; rr++)
            atomicAdd(S + b * HID + 16 * w + 4 * q + rr, aS[rr]);
    }
}

// K3: fused wmk + statsk, 4 channels per block (grid 256). Each thread
// register-caches its M-row and G-row ONCE, reused for 4 channels.
__global__ __launch_bounds__(512, 1) void wmstat(
    const float* __restrict__ ww, const float* __restrict__ Mm,
    const float* __restrict__ S, const float* __restrict__ G,
    const float* __restrict__ wb, const float* __restrict__ gamma,
    const float* __restrict__ beta, unsigned short* __restrict__ wmbf,
    float* __restrict__ scale, float* __restrict__ shift2)
{
    const int c0 = blockIdx.x * 4;
    const int t = threadIdx.x;
    const int b = t >> 6, lane = t & 63;

    f32x4 mrow[16], grow[16];
    {
        const f32x4* mr4 = (const f32x4*)(Mm + ((size_t)b * HID + lane) * HID);
        const f32x4* gr4 = (const f32x4*)(G  + (size_t)b * HID * HID + (size_t)lane * HID);
#pragma unroll
        for (int i = 0; i < 16; i++) mrow[i] = mr4[i];
#pragma unroll
        for (int i = 0; i < 16; i++) grow[i] = gr4[i];
    }
    const float sv = S[b * HID + lane];

    __shared__ float vsh[8][64];
    __shared__ float red[4][16];

#pragma unroll
    for (int ci = 0; ci < 4; ci++) {
        const int c = c0 + ci;
        const float wbc = wb[c];
        const float* wr = ww + (size_t)c * HID;

        float acc = 0.f;
#pragma unroll
        for (int d = 0; d < 16; d++) {
            f32x4 w4 = *(const f32x4*)(wr + 4 * d);
            acc += w4[0] * mrow[d][0] + w4[1] * mrow[d][1]
                 + w4[2] * mrow[d][2] + w4[3] * mrow[d][3];
        }
        unsigned short us = f2bf(acc * (1.0f / N_));
        wmbf[((size_t)b * C_ + c) * HID + lane] = us;
        float v = bf2f(us);
        float t1 = v * sv;
        for (int off = 32; off; off >>= 1) t1 += __shfl_down(t1, off);
        t1 = __shfl(t1, 0);

        __syncthreads();
        vsh[b][lane] = v;
        __syncthreads();

        const f32x4* vb4 = (const f32x4*)&vsh[b][0];
        float inner = 0.f;
#pragma unroll
        for (int fo = 0; fo < 16; fo++) {
            f32x4 vv = vb4[fo];
            inner = fmaf(grow[fo][0], vv[0], inner);
            inner = fmaf(grow[fo][1], vv[1], inner);
            inner = fmaf(grow[fo][2], vv[2], inner);
            inner = fmaf(grow[fo][3], vv[3], inner);
        }
        float qq = v * inner;
        for (int off = 32; off; off >>= 1) qq += __shfl_down(qq, off);
        qq = __shfl(qq, 0);

        if (lane == 0) {
            red[ci][b] = t1;
            red[ci][8 + b] = qq + 2.f * wbc * t1;
        }
    }
    __syncthreads();
    if (t < 4) {
        const int c = c0 + t;
        float asum = 0.f, asq = 0.f;
#pragma unroll
        for (int i = 0; i < 8; i++) { asum += red[t][i]; asq += red[t][8 + i]; }
        const float wbc = wb[c];
        const float cnt = (float)B_ * (float)N_;
        const float inv = 1.0f / cnt;
        float mean = (asum + cnt * wbc) * inv;
        float e2   = (asq + cnt * wbc * wbc) * inv;
        float var  = e2 - mean * mean;
        float sc   = gamma[c] * rsqrtf(var + 1e-5f);
        scale[c]  = sc;
        shift2[c] = beta[c] - mean * sc + sc * wbc;
    }
}

// K4: out = sc[c]*(Wm[b][c][:]·theta[:,n]) + sh[c] + x.
// 32x32x16 MFMA; per-instruction x/out access = 2x128B contiguous.
__global__ __launch_bounds__(256) void finalk_mfma(
    const unsigned short* __restrict__ wmbf, const unsigned short* __restrict__ thT,
    const float* __restrict__ x, const float* __restrict__ scale,
    const float* __restrict__ shift2, float* __restrict__ out)
{
    const int b = blockIdx.z, c0 = blockIdx.y * 32, n0b = blockIdx.x * 128;
    const int t = threadIdx.x, w = t >> 6, L = t & 63;
    const int n0 = n0b + w * 32;
    const int rr = L & 31, kh = L >> 5;

    const unsigned short* apw = wmbf + ((size_t)b * C_ + c0 + rr) * HID + kh * 8;
    const unsigned short* bpt = thT + ((size_t)b * N_ + n0 + rr) * HID + kh * 8;

    float xv[16];
#pragma unroll
    for (int r = 0; r < 16; r++) {
        int cl = (r & 3) + 8 * (r >> 2) + 4 * kh;
        xv[r] = x[((size_t)b * C_ + c0 + cl) * N_ + n0 + rr];
    }

    f32x16 acc = {};
#pragma unroll
    for (int kk = 0; kk < 4; kk++) {
        bf16x8 A  = *(const bf16x8*)(apw + kk * 16);
        bf16x8 Bv = *(const bf16x8*)(bpt + kk * 16);
        acc = __builtin_amdgcn_mfma_f32_32x32x16_bf16(A, Bv, acc, 0, 0, 0);
    }

#pragma unroll
    for (int r = 0; r < 16; r++) {
        int cl = (r & 3) + 8 * (r >> 2) + 4 * kh;
        int c  = c0 + cl;
        size_t off = ((size_t)b * C_ + c) * N_ + n0 + rr;
        out[off] = fmaf(scale[c], acc[r], shift2[c]) + xv[r];
    }
}

extern "C" void kernel_launch(void* const* d_in, const int* in_sizes, int n_in,
                              void* d_out, int out_size, void* d_ws, size_t ws_size,
                              hipStream_t stream)
{
    const float* x  = (const float*)d_in[0];
    const float* tw = (const float*)d_in[1];
    const float* tb = (const float*)d_in[2];
    const float* pw = (const float*)d_in[3];
    const float* pb = (const float*)d_in[4];
    const float* gw = (const float*)d_in[5];
    const float* gb = (const float*)d_in[6];
    const float* ww = (const float*)d_in[7];
    const float* wb = (const float*)d_in[8];
    const float* gamma = (const float*)d_in[9];
    const float* beta  = (const float*)d_in[10];
    float* out = (float*)d_out;

    char* ws = (char*)d_ws;
    unsigned short* wbf   = (unsigned short*)(ws + WSB_WBF);
    unsigned short* thT   = (unsigned short*)(ws + WSB_THT);
    float* Mm   = (float*)(ws + WSB_M);
    float* Gg   = (float*)(ws + WSB_G);
    float* S    = (float*)(ws + WSB_S);
    unsigned short* wmbf = (unsigned short*)(ws + WSB_WMBF);
    float* scl  = (float*)(ws + WSB_SC);
    float* shf  = (float*)(ws + WSB_SH);

    wcvt<<<dim3(RTOT * 1024 / 256), 256, 0, stream>>>(tw, pw, gw, wbf, Mm);
    projx_mfma<<<dim3(64, B_), 256, 0, stream>>>(x, wbf, tb, pb, gb, thT, Mm, Gg, S);
    wmstat<<<C_ / 4, 512, 0, stream>>>(ww, Mm, S, Gg, wb, gamma, beta, wmbf, scl, shf);
    finalk_mfma<<<dim3(16, 32, B_), 256, 0, stream>>>(wmbf, thT, x, scl, shf, out);
}

// Round 16
// 192.636 us; speedup vs baseline: 1.0102x; 1.0098x over previous
//
#include <hip/hip_runtime.h>

#define B_    8
#define C_    1024
#define HID   64
#define N_    2048
#define RTOT  192

typedef __attribute__((ext_vector_type(8))) short   bf16x8;
typedef __attribute__((ext_vector_type(4))) unsigned short ush4;
typedef __attribute__((ext_vector_type(4))) float   f32x4;
typedef __attribute__((ext_vector_type(16))) float  f32x16;

// ---- workspace byte offsets ----
#define WSB_WBF   ((size_t)0)          // [192][1024]     bf16
#define WSB_TPG   ((size_t)393216)     // [B][192][2048]  bf16
#define WSB_THT   ((size_t)6684672)    // [B][2048][64]   bf16
#define WSB_M     ((size_t)8781824)    // [B][64][64]     f32
#define WSB_G     ((size_t)8912896)    // [B][64][64]     f32
#define WSB_S     ((size_t)9043968)    // [B][64]         f32 (contiguous after G)
#define WSB_WMBF  ((size_t)9046016)    // [B][1024][64]   bf16
#define WSB_SC    ((size_t)10094592)   // [1024] f32
#define WSB_SH    ((size_t)10098688)   // [1024] f32

#define MGS_FLOATS (2 * B_ * HID * HID + B_ * HID)   // 66048

static __device__ __forceinline__ unsigned short f2bf(float f) {
    union { float f; unsigned u; } v; v.f = f;
    unsigned r = v.u + 0x7fffu + ((v.u >> 16) & 1u);
    return (unsigned short)(r >> 16);
}
static __device__ __forceinline__ float bf2f(unsigned short h) {
    union { unsigned u; float f; } v; v.u = ((unsigned)h) << 16;
    return v.f;
}

// async global->LDS DMA, 16B per lane. LDS dest must be linear in lane order.
static __device__ __forceinline__ void gload16(const unsigned short* g, unsigned short* l) {
    __builtin_amdgcn_global_load_lds(
        (const __attribute__((address_space(1))) unsigned int*)g,
        (__attribute__((address_space(3))) unsigned int*)l, 16, 0, 0);
}

// K0: weights -> bf16 (concat theta/phi/g) + zero M|G|S (absorbs the memset).
__global__ __launch_bounds__(256) void wcvt(
    const float* __restrict__ tw, const float* __restrict__ pw,
    const float* __restrict__ gw, unsigned short* __restrict__ wbf,
    float* __restrict__ mgs)
{
    int idx = blockIdx.x * 256 + threadIdx.x;
    if (blockIdx.x < 258) {
        int z = blockIdx.x * 256 + threadIdx.x;
        if (z < MGS_FLOATS) mgs[z] = 0.f;
    }
    int r = idx >> 10, k = idx & 1023;
    float v = (r < 64) ? tw[(size_t)r * 1024 + k]
            : (r < 128) ? pw[(size_t)(r - 64) * 1024 + k]
                        : gw[(size_t)(r - 128) * 1024 + k];
    wbf[idx] = f2bf(v);
}

// K1: fused transpose + projection GEMM — T4 counted-vmcnt pipeline.
// Block = 32n x ALL 192r (grid 64 x 8, 512 blocks, 2/CU): x read ONCE.
// 4 waves: wn (16n half) x wc (96r half, 6 B-frags). Reg-staged A (T14),
// gload_lds-staged B (6 chunks/step), steady-state vmcnt(2), one barrier/step.
// Swizzles: A sw(n) = (n ^ (n>>3)) & 7 on 16B slots (write/read matched);
// B slot ^= row&7.
__global__ __launch_bounds__(256, 2) void projx_mfma(
    const float* __restrict__ x, const unsigned short* __restrict__ wbf,
    const float* __restrict__ tb, const float* __restrict__ pb,
    const float* __restrict__ gb, unsigned short* __restrict__ tpgbf,
    unsigned short* __restrict__ thT)
{
    const int b = blockIdx.y, n0 = blockIdx.x * 32;
    const int t = threadIdx.x, w = t >> 6, L = t & 63;
    const int wn = w & 1, wc = w >> 1;          // wc in {0,1}: 96-row half
    const int lr = L & 15, q = L >> 4;

    __shared__ unsigned short Abuf[2][32][64];   // 8 KB
    __shared__ unsigned short Bbuf[2][192][64];  // 48 KB

    f32x4 acc[6] = {};

    // x staging: thread covers c-pair g (rows 2g,2g+1), n-quad n4.
    const int n4 = t & 7;        // 0..7  (n_local = 4*n4..4*n4+3)
    const int g  = t >> 3;       // 0..31 (c-pair)
    const float* xbase = x + (size_t)b * C_ * N_ + n0 + n4 * 4;

    f32x4 vr[2];
    auto loadX = [&](int s) {
        const float* p = xbase + (size_t)(64 * s + 2 * g) * N_;
        vr[0] = *(const f32x4*)(p);
        vr[1] = *(const f32x4*)(p + N_);
    };
    auto writeA = [&](int cb) {
#pragma unroll
        for (int rrow = 0; rrow < 4; rrow++) {
            int n  = 4 * n4 + rrow;              // 0..31
            int sw = (n ^ (n >> 3)) & 7;
            int ss = (g >> 2) ^ sw;
            unsigned val = (unsigned)f2bf(vr[0][rrow]) | ((unsigned)f2bf(vr[1][rrow]) << 16);
            ((unsigned*)&Abuf[cb][n][0])[ss * 4 + (g & 3)] = val;
        }
    };
    auto stageB = [&](int cb, int s) {
        const int k0 = 64 * s;
#pragma unroll
        for (int i = 0; i < 6; i++) {            // B: 24 KB = 6 chunks
            int o = (i * 256 + t) * 16;
            int row = o >> 7, slot = (o >> 4) & 7, ss = slot ^ (row & 7);
            gload16(wbf + ((size_t)row) * 1024 + k0 + ss * 8,
                    &Bbuf[cb][0][0] + o / 2);
        }
    };

    const int swB = lr & 7;
    const int nfa = wn * 16 + lr;                // 0..31
    const int swA = (nfa ^ (nfa >> 3)) & 7;
    auto compute = [&](int cur) {
#pragma unroll
        for (int ksub = 0; ksub < 2; ksub++) {
            bf16x8 Af = *(const bf16x8*)&Abuf[cur][nfa][((ksub * 4 + q) ^ swA) * 8];
            bf16x8 Bf[6];
#pragma unroll
            for (int j = 0; j < 6; j++)
                Bf[j] = *(const bf16x8*)&Bbuf[cur][wc * 96 + j * 16 + lr]
                                              [((ksub * 4 + q) ^ swB) * 8];
#pragma unroll
            for (int j = 0; j < 6; j++)
                acc[j] = __builtin_amdgcn_mfma_f32_16x16x32_bf16(
                    Af, Bf[j], acc[j], 0, 0, 0);
        }
    };

    // ---- prologue ----
    loadX(0);
    asm volatile("s_waitcnt vmcnt(0)" ::: "memory");
    writeA(0);
    stageB(0, 0);                 // 6 ops
    loadX(1);                     // 2 ops -> 8 outstanding
    asm volatile("s_waitcnt vmcnt(2)" ::: "memory");   // B0 landed, X1 flying
    asm volatile("s_waitcnt lgkmcnt(0)" ::: "memory");
    __builtin_amdgcn_s_barrier();

    int cur = 0;
    for (int s = 0; s < 16; s++) {
        if (s < 15) {
            writeA(cur ^ 1);      // consumes X(s+1) (compiler-inserted vm wait)
            stageB(cur ^ 1, s + 1);
        }
        if (s < 14) loadX(s + 2);
        compute(cur);
        if (s < 14)
            asm volatile("s_waitcnt vmcnt(2)" ::: "memory");  // B(s+1) done
        else
            asm volatile("s_waitcnt vmcnt(0)" ::: "memory");
        asm volatile("s_waitcnt lgkmcnt(0)" ::: "memory");
        if (s < 15) __builtin_amdgcn_s_barrier();
        cur ^= 1;
    }

#pragma unroll
    for (int j = 0; j < 6; j++) {
        int rcol = 96 * wc + 16 * j + lr;
        float bias = (rcol < 64) ? tb[rcol]
                   : (rcol < 128) ? pb[rcol - 64] : gb[rcol - 128];
        ush4 o;
#pragma unroll
        for (int rr = 0; rr < 4; rr++) o[rr] = f2bf(acc[j][rr] + bias);
        int nglob = n0 + wn * 16 + q * 4;
        *(ush4*)(tpgbf + ((size_t)b * RTOT + rcol) * N_ + nglob) = o;
        if (rcol < HID) {   // theta rows: transposed copy for finalk
#pragma unroll
            for (int rr = 0; rr < 4; rr++)
                thT[((size_t)b * N_ + nglob + rr) * HID + rcol] = o[rr];
        }
    }
}

// K2: gram products via MFMA, k-split (16 chunks), atomicAdd into zeroed
// M|G|S. p==0: M = phi·g^T ; p==1: G = theta·theta^T plus S = theta·1.
__global__ __launch_bounds__(256) void gram_mfma(
    const unsigned short* __restrict__ tpgbf, float* __restrict__ Mm,
    float* __restrict__ Gg, float* __restrict__ S)
{
    const int kc = blockIdx.x, p = blockIdx.y, b = blockIdx.z;
    const int t = threadIdx.x, w = t >> 6, L = t & 63;
    const int lr = L & 15, q = L >> 4;
    const unsigned short* base = tpgbf + (size_t)b * RTOT * N_;
    const unsigned short* Arow = base + (p ? 0 : (size_t)64 * N_);
    const unsigned short* Brow = base + (p ? 0 : (size_t)128 * N_);
    const unsigned short* ap = Arow + ((size_t)(16 * w + lr)) * N_ + kc * 128 + q * 8;
    const unsigned short* bp = Brow + ((size_t)lr) * N_ + kc * 128 + q * 8;

    bf16x8 ones;
#pragma unroll
    for (int j = 0; j < 8; j++) ones[j] = (short)0x3F80;

    f32x4 acc[4] = {};
    f32x4 accs = {};
#pragma unroll
    for (int it = 0; it < 4; ++it) {
        const int kn = it * 32;
        bf16x8 a = *(const bf16x8*)(ap + kn);
#pragma unroll
        for (int g = 0; g < 4; g++) {
            bf16x8 bb = *(const bf16x8*)(bp + (size_t)g * 16 * N_ + kn);
            acc[g] = __builtin_amdgcn_mfma_f32_16x16x32_bf16(a, bb, acc[g], 0, 0, 0);
        }
        if (p) accs = __builtin_amdgcn_mfma_f32_16x16x32_bf16(a, ones, accs, 0, 0, 0);
    }
    float* outp = (p ? Gg : Mm) + (size_t)b * HID * HID;
#pragma unroll
    for (int g = 0; g < 4; g++)
#pragma unroll
        for (int r = 0; r < 4; r++) {
            int row = 16 * w + q * 4 + r, col = 16 * g + lr;
            atomicAdd(outp + row * HID + col, acc[g][r]);
        }
    if (p && lr == 0) {
#pragma unroll
        for (int r = 0; r < 4; r++)
            atomicAdd(S + b * HID + 16 * w + q * 4 + r, accs[r]);
    }
}

// K3: fused wmk + statsk, 4 channels per block (grid 256). Each thread
// register-caches its M-row and G-row ONCE, reused for 4 channels.
__global__ __launch_bounds__(512, 1) void wmstat(
    const float* __restrict__ ww, const float* __restrict__ Mm,
    const float* __restrict__ S, const float* __restrict__ G,
    const float* __restrict__ wb, const float* __restrict__ gamma,
    const float* __restrict__ beta, unsigned short* __restrict__ wmbf,
    float* __restrict__ scale, float* __restrict__ shift2)
{
    const int c0 = blockIdx.x * 4;
    const int t = threadIdx.x;
    const int b = t >> 6, lane = t & 63;

    f32x4 mrow[16], grow[16];
    {
        const f32x4* mr4 = (const f32x4*)(Mm + ((size_t)b * HID + lane) * HID);
        const f32x4* gr4 = (const f32x4*)(G  + (size_t)b * HID * HID + (size_t)lane * HID);
#pragma unroll
        for (int i = 0; i < 16; i++) mrow[i] = mr4[i];
#pragma unroll
        for (int i = 0; i < 16; i++) grow[i] = gr4[i];
    }
    const float sv = S[b * HID + lane];

    __shared__ float vsh[8][64];
    __shared__ float red[4][16];

#pragma unroll
    for (int ci = 0; ci < 4; ci++) {
        const int c = c0 + ci;
        const float wbc = wb[c];
        const float* wr = ww + (size_t)c * HID;

        float acc = 0.f;
#pragma unroll
        for (int d = 0; d < 16; d++) {
            f32x4 w4 = *(const f32x4*)(wr + 4 * d);
            acc += w4[0] * mrow[d][0] + w4[1] * mrow[d][1]
                 + w4[2] * mrow[d][2] + w4[3] * mrow[d][3];
        }
        unsigned short us = f2bf(acc * (1.0f / N_));
        wmbf[((size_t)b * C_ + c) * HID + lane] = us;
        float v = bf2f(us);
        float t1 = v * sv;
        for (int off = 32; off; off >>= 1) t1 += __shfl_down(t1, off);
        t1 = __shfl(t1, 0);

        __syncthreads();
        vsh[b][lane] = v;
        __syncthreads();

        const f32x4* vb4 = (const f32x4*)&vsh[b][0];
        float inner = 0.f;
#pragma unroll
        for (int fo = 0; fo < 16; fo++) {
            f32x4 vv = vb4[fo];
            inner = fmaf(grow[fo][0], vv[0], inner);
            inner = fmaf(grow[fo][1], vv[1], inner);
            inner = fmaf(grow[fo][2], vv[2], inner);
            inner = fmaf(grow[fo][3], vv[3], inner);
        }
        float qq = v * inner;
        for (int off = 32; off; off >>= 1) qq += __shfl_down(qq, off);
        qq = __shfl(qq, 0);

        if (lane == 0) {
            red[ci][b] = t1;
            red[ci][8 + b] = qq + 2.f * wbc * t1;
        }
    }
    __syncthreads();
    if (t < 4) {
        const int c = c0 + t;
        float asum = 0.f, asq = 0.f;
#pragma unroll
        for (int i = 0; i < 8; i++) { asum += red[t][i]; asq += red[t][8 + i]; }
        const float wbc = wb[c];
        const float cnt = (float)B_ * (float)N_;
        const float inv = 1.0f / cnt;
        float mean = (asum + cnt * wbc) * inv;
        float e2   = (asq + cnt * wbc * wbc) * inv;
        float var  = e2 - mean * mean;
        float sc   = gamma[c] * rsqrtf(var + 1e-5f);
        scale[c]  = sc;
        shift2[c] = beta[c] - mean * sc + sc * wbc;
    }
}

// K4: out = sc[c]*(Wm[b][c][:]·theta[:,n]) + sh[c] + x.
// 32x32x16 MFMA; per-instruction x/out access = 2x128B contiguous.
__global__ __launch_bounds__(256) void finalk_mfma(
    const unsigned short* __restrict__ wmbf, const unsigned short* __restrict__ thT,
    const float* __restrict__ x, const float* __restrict__ scale,
    const float* __restrict__ shift2, float* __restrict__ out)
{
    const int b = blockIdx.z, c0 = blockIdx.y * 32, n0b = blockIdx.x * 128;
    const int t = threadIdx.x, w = t >> 6, L = t & 63;
    const int n0 = n0b + w * 32;
    const int rr = L & 31, kh = L >> 5;

    const unsigned short* apw = wmbf + ((size_t)b * C_ + c0 + rr) * HID + kh * 8;
    const unsigned short* bpt = thT + ((size_t)b * N_ + n0 + rr) * HID + kh * 8;

    float xv[16];
#pragma unroll
    for (int r = 0; r < 16; r++) {
        int cl = (r & 3) + 8 * (r >> 2) + 4 * kh;
        xv[r] = x[((size_t)b * C_ + c0 + cl) * N_ + n0 + rr];
    }

    f32x16 acc = {};
#pragma unroll
    for (int kk = 0; kk < 4; kk++) {
        bf16x8 A  = *(const bf16x8*)(apw + kk * 16);
        bf16x8 Bv = *(const bf16x8*)(bpt + kk * 16);
        acc = __builtin_amdgcn_mfma_f32_32x32x16_bf16(A, Bv, acc, 0, 0, 0);
    }

#pragma unroll
    for (int r = 0; r < 16; r++) {
        int cl = (r & 3) + 8 * (r >> 2) + 4 * kh;
        int c  = c0 + cl;
        size_t off = ((size_t)b * C_ + c) * N_ + n0 + rr;
        out[off] = fmaf(scale[c], acc[r], shift2[c]) + xv[r];
    }
}

extern "C" void kernel_launch(void* const* d_in, const int* in_sizes, int n_in,
                              void* d_out, int out_size, void* d_ws, size_t ws_size,
                              hipStream_t stream)
{
    const float* x  = (const float*)d_in[0];
    const float* tw = (const float*)d_in[1];
    const float* tb = (const float*)d_in[2];
    const float* pw = (const float*)d_in[3];
    const float* pb = (const float*)d_in[4];
    const float* gw = (const float*)d_in[5];
    const float* gb = (const float*)d_in[6];
    const float* ww = (const float*)d_in[7];
    const float* wb = (const float*)d_in[8];
    const float* gamma = (const float*)d_in[9];
    const float* beta  = (const float*)d_in[10];
    float* out = (float*)d_out;

    char* ws = (char*)d_ws;
    unsigned short* wbf   = (unsigned short*)(ws + WSB_WBF);
    unsigned short* tpgbf = (unsigned short*)(ws + WSB_TPG);
    unsigned short* thT   = (unsigned short*)(ws + WSB_THT);
    float* Mm   = (float*)(ws + WSB_M);
    float* Gg   = (float*)(ws + WSB_G);
    float* S    = (float*)(ws + WSB_S);
    unsigned short* wmbf = (unsigned short*)(ws + WSB_WMBF);
    float* scl  = (float*)(ws + WSB_SC);
    float* shf  = (float*)(ws + WSB_SH);

    wcvt<<<dim3(RTOT * 1024 / 256), 256, 0, stream>>>(tw, pw, gw, wbf, Mm);
    projx_mfma<<<dim3(64, B_), 256, 0, stream>>>(x, wbf, tb, pb, gb, tpgbf, thT);
    gram_mfma<<<dim3(16, 2, B_), 256, 0, stream>>>(tpgbf, Mm, Gg, S);
    wmstat<<<C_ / 4, 512, 0, stream>>>(ww, Mm, S, Gg, wb, gamma, beta, wmbf, scl, shf);
    finalk_mfma<<<dim3(16, 32, B_), 256, 0, stream>>>(wmbf, thT, x, scl, shf, out);
}